// Round 11
// baseline (197.342 us; speedup 1.0000x reference)
//
#include <hip/hip_runtime.h>

// GPT-2 attention block, B=4 S=2048 D=1024 H=16 DH=64, f32 in/out.
// GEMMs (R4-proven, FROZEN): 16x16x32 bf16 MFMA, 128x128 tile, BK=32, 4 waves,
//   3 LDS buffers, counted vmcnt(4), source-side XOR-swizzled gll16 staging.
// Attention (R11): qt-PAIRED blocks (qt=p then 15-p -> uniform 34 tiles/block,
//   512 blocks all co-resident), 3-buf gll16 DMA vmcnt(4) pipeline flat across
//   the half boundary, tree-reduced softmax (4-partial max/sum).
// Layouts (gfx950):
//   16x16x32: A[l&15][8*(l>>4)+e], B[l&15][8*(l>>4)+e], D[4*(l>>4)+r][l&15]
//   32x32x16: A[l&31][8*(l>>5)+e], B[l&31][8*(l>>5)+e],
//             D[(r&3)+8*(r>>2)+4*(l>>5)][l&31]
// LESSON (R9): 256^2/8-wave acc needs ~200 VGPR -> __launch_bounds__ minwave
//   >=4 forces full accumulator spill (VGPR=64, 1.4GB scratch). Do not retry.
// LESSON (R10): attn grid 1024 + 48KB LDS = 3/CU residency + imbalance ->
//   uniform-work pairing beats LPT ordering; residency arithmetic first.

typedef short  s8v   __attribute__((ext_vector_type(8)));  // 8 bf16 (16B)
typedef float  f32x4 __attribute__((ext_vector_type(4)));
typedef float  f32x16 __attribute__((ext_vector_type(16)));
typedef unsigned short u16;
typedef u16    u16x4 __attribute__((ext_vector_type(4)));
typedef unsigned int u32;
typedef u32    u32x2 __attribute__((ext_vector_type(2)));

__device__ __forceinline__ u16 f2b(float f) {
  union { float f; unsigned u; } v; v.f = f;
  unsigned r = v.u + 0x7FFFu + ((v.u >> 16) & 1u);   // RNE
  return (u16)(r >> 16);
}
__device__ __forceinline__ u32 cvtpk(float lo, float hi) {   // bf16(lo)|bf16(hi)<<16
  u32 r; asm("v_cvt_pk_bf16_f32 %0, %1, %2" : "=v"(r) : "v"(lo), "v"(hi)); return r;
}
__device__ __forceinline__ void plswap(u32 &d, u32 &s) {
  asm volatile("v_permlane32_swap_b32 %0, %1" : "+v"(d), "+v"(s));
}
__device__ __forceinline__ void gll16(const void* g, void* l) {
  __builtin_amdgcn_global_load_lds((const __attribute__((address_space(1))) void*)g,
                                   (__attribute__((address_space(3))) void*)l, 16, 0, 0);
}

#define QSCALE 0.18033688011112042f   // 0.125 * log2(e): softmax in exp2 domain

// ---------------- f32 -> bf16 elementwise ----------------
__global__ __launch_bounds__(256) void k_cvt(const float* __restrict__ in,
                                             u16* __restrict__ out, int n4) {
  int t = blockIdx.x * 256 + threadIdx.x;
  if (t < n4) {
    f32x4 f = ((const f32x4*)in)[t];
    u16x4 o;
    o[0] = f2b(f[0]); o[1] = f2b(f[1]); o[2] = f2b(f[2]); o[3] = f2b(f[3]);
    ((u16x4*)out)[t] = o;
  }
}

// ---------------- f32 [R][C] -> bf16 [C][R] transpose ----------------
__global__ __launch_bounds__(256) void k_tr(const float* __restrict__ in,
                                            u16* __restrict__ out, int R, int C) {
  __shared__ float tile[32][33];
  int c0 = blockIdx.x * 32, r0 = blockIdx.y * 32;
  int tx = threadIdx.x, ty = threadIdx.y;
#pragma unroll
  for (int j = 0; j < 4; j++)
    tile[ty + j * 8][tx] = in[(size_t)(r0 + ty + j * 8) * C + c0 + tx];
  __syncthreads();
#pragma unroll
  for (int j = 0; j < 4; j++)
    out[(size_t)(c0 + ty + j * 8) * R + r0 + tx] = f2b(tile[tx][ty + j * 8]);
}

// ---- one K-tile of MFMA work: 8 swizzled ds_read_b128 + 16 MFMA (setprio'd) ----
__device__ __forceinline__ void gemm_tile(const u16* bA, const u16* bB,
                                          f32x4 (&acc)[4][4],
                                          int wr, int wc, int lr, int lg) {
  s8v af[4], bfr[4];
#pragma unroll
  for (int m = 0; m < 4; m++) {
    const int row = wr + m * 16 + lr;
    af[m] = *(const s8v*)&bA[row * 32 + (lg ^ ((row >> 1) & 3)) * 8];
  }
#pragma unroll
  for (int n = 0; n < 4; n++) {
    const int row = wc + n * 16 + lr;
    bfr[n] = *(const s8v*)&bB[row * 32 + (lg ^ ((row >> 1) & 3)) * 8];
  }
  __builtin_amdgcn_s_setprio(1);
#pragma unroll
  for (int m = 0; m < 4; m++)
#pragma unroll
    for (int n = 0; n < 4; n++)
      acc[m][n] = __builtin_amdgcn_mfma_f32_16x16x32_bf16(af[m], bfr[n], acc[m][n], 0, 0, 0);
  __builtin_amdgcn_s_setprio(0);
}

// ---------------- bf16 GEMM: C[M,N] = A[M,K] @ Bt[N,K]^T (+bias) ----------------
template <int EPI>
__global__ __launch_bounds__(256, 3) void k_gemm(
    const u16* __restrict__ A, const u16* __restrict__ Bt,
    const float* __restrict__ bias,
    u16* __restrict__ qb, u16* __restrict__ kb, u16* __restrict__ vb,
    float* __restrict__ outf, int M, int N, int K) {
  __shared__ u16 lA[3][4096];     // [buf][128 rows][32 cols], 16B-cell swizzled
  __shared__ u16 lB[3][4096];
  const int tid = threadIdx.x;
  const int lane = tid & 63, w = tid >> 6;
  const int wr = (w >> 1) * 64, wc = (w & 1) * 64;
  const int lr = lane & 15, lg = lane >> 4;

  const int nwg = gridDim.x * gridDim.y;
  const int bid = blockIdx.y * gridDim.x + blockIdx.x;
  const int swz = (bid & 7) * (nwg >> 3) + (bid >> 3);
  const int m0 = (swz / gridDim.x) * 128, n0 = (swz % gridDim.x) * 128;

  const int rr = lane >> 2;
  const int cb = ((lane & 3) ^ ((lane >> 3) & 3)) * 16;
  const size_t K2 = (size_t)K * 2;
  const char* gAc = (const char*)A + (size_t)m0 * K2;
  const char* gBc = (const char*)Bt + (size_t)n0 * K2;

  auto stage = [&](int kt, int buf) {
    const size_t ko = (size_t)kt * 64 + cb;
    char* dA = (char*)&lA[buf][0];
    char* dB = (char*)&lB[buf][0];
    gll16(gAc + (size_t)(32 * w + rr) * K2 + ko,      dA + (2 * w) * 1024);
    gll16(gAc + (size_t)(32 * w + 16 + rr) * K2 + ko, dA + (2 * w + 1) * 1024);
    gll16(gBc + (size_t)(32 * w + rr) * K2 + ko,      dB + (2 * w) * 1024);
    gll16(gBc + (size_t)(32 * w + 16 + rr) * K2 + ko, dB + (2 * w + 1) * 1024);
  };

  f32x4 acc[4][4];
  f32x4 zz = {0.f, 0.f, 0.f, 0.f};
#pragma unroll
  for (int m = 0; m < 4; m++)
#pragma unroll
    for (int n = 0; n < 4; n++) acc[m][n] = zz;

  const int nk = K / 32;
  stage(0, 0);
  if (nk > 1) stage(1, 1);

#define STEP(T, CB, SB)                                                     \
  if ((T) < nk) {                                                           \
    if ((T) + 1 < nk) { asm volatile("s_waitcnt vmcnt(4)" ::: "memory"); }  \
    else              { asm volatile("s_waitcnt vmcnt(0)" ::: "memory"); }  \
    __builtin_amdgcn_s_barrier();                                           \
    __builtin_amdgcn_sched_barrier(0);                                      \
    if ((T) + 2 < nk) stage((T) + 2, (SB));                                 \
    gemm_tile(&lA[(CB)][0], &lB[(CB)][0], acc, wr, wc, lr, lg);             \
  }

  for (int t0 = 0; t0 < nk; t0 += 3) {
    STEP(t0,     0, 2)
    STEP(t0 + 1, 1, 0)
    STEP(t0 + 2, 2, 1)
  }
#undef STEP

#pragma unroll
  for (int m = 0; m < 4; m++) {
#pragma unroll
    for (int n = 0; n < 4; n++) {
      const int col = n0 + wc + n * 16 + lr;
      const float bb = bias[col];
      const int row0 = m0 + wr + m * 16 + 4 * lg;
      if (EPI == 0) {
        const int which = col >> 10, d = col & 1023, h = d >> 6, dh = d & 63;
        if (which == 2) {
          const int b = row0 >> 11, s = row0 & 2047;
          u16x4 ov;
#pragma unroll
          for (int r = 0; r < 4; r++) ov[r] = f2b(acc[m][n][r] + bb);
          *(u16x4*)(vb + ((size_t)((b * 16 + h) * 64 + dh)) * 2048 + s) = ov;
        } else {
          u16* dst = which == 0 ? qb : kb;
          const float sc = which == 0 ? QSCALE : 1.0f;
#pragma unroll
          for (int r = 0; r < 4; r++) {
            const int row = row0 + r;
            const int b = row >> 11, s = row & 2047;
            dst[(size_t)((b * 16 + h) * 2048 + s) * 64 + dh] = f2b((acc[m][n][r] + bb) * sc);
          }
        }
      } else {
#pragma unroll
        for (int r = 0; r < 4; r++)
          outf[(size_t)(row0 + r) * N + col] = acc[m][n][r] + bb;
      }
    }
  }
}

// ---------------- flash attention, causal, qt-paired, in-reg softmax ----------------
// grid 512 = (bh, pair). Block does qt=pair then qt=15-pair -> uniform 34 KV
// tiles. 3-buf gll16 DMA, vmcnt(4), pipeline flat across the half boundary.
__global__ __launch_bounds__(256, 3) void k_attn(
    const u16* __restrict__ Q, const u16* __restrict__ K,
    const u16* __restrict__ Vt, u16* __restrict__ O) {
  __shared__ u16 lKV[3][8192];     // [buf][ K: 4096 u16 | V: 4096 u16 ] = 48 KB
  const int x = blockIdx.x;
  const int bh = ((x & 7) << 3) | (x >> 6);      // x&7 = bh>>3 -> 8 bh / XCD (4MB KV = L2)
  const int pair = (x >> 3) & 7;
  const int tid = threadIdx.x, lane = tid & 63, w = tid >> 6;
  const int l31 = lane & 31, h = lane >> 5;
  const u16* Kb = K + (size_t)bh * 2048 * 64;
  const u16* Vb = Vt + (size_t)bh * 64 * 2048;
  const int b_ = bh >> 4, h_ = bh & 15;

  const int n0 = 2 * pair + 2;                   // tiles in half 0; total 34
  auto kvof = [&](int f) { return (f < n0 ? f : f - n0) * 64; };

  auto stage_dma = [&](int kv0, int buf) {
    char* base = (char*)&lKV[buf][0];
#pragma unroll
    for (int i = 0; i < 2; i++) {
      const int sg = 2 * w + i;
      const int r = lane ^ sg;
      gll16(Kb + (size_t)(kv0 + r) * 64 + sg * 8, base + sg * 1024);
      gll16(Vb + (size_t)r * 2048 + kv0 + sg * 8, base + 8192 + sg * 1024);
    }
  };

  int qbase = pair * 128 + w * 32;
  s8v qf[4];
  auto loadQ = [&]() {
#pragma unroll
    for (int ks = 0; ks < 4; ks++)
      qf[ks] = *(const s8v*)(Q + (size_t)(bh * 2048 + qbase + l31) * 64 + ks * 16 + 8 * h);
  };
  loadQ();

  f32x16 accO0, accO1;
#pragma unroll
  for (int i = 0; i < 16; i++) { accO0[i] = 0.f; accO1[i] = 0.f; }
  float mrun = -1e30f, lrun = 0.f;

  auto epilogue = [&]() {
    const float rinv = 1.0f / lrun;
    u16* Ob = O + (size_t)(b_ * 2048 + qbase + l31) * 1024 + h_ * 64;
#pragma unroll
    for (int a = 0; a < 4; a++) {
      u32x2 o0, o1;
      o0[0] = cvtpk(accO0[4 * a] * rinv, accO0[4 * a + 1] * rinv);
      o0[1] = cvtpk(accO0[4 * a + 2] * rinv, accO0[4 * a + 3] * rinv);
      o1[0] = cvtpk(accO1[4 * a] * rinv, accO1[4 * a + 1] * rinv);
      o1[1] = cvtpk(accO1[4 * a + 2] * rinv, accO1[4 * a + 3] * rinv);
      *(u32x2*)(Ob + 8 * a + 4 * h) = o0;
      *(u32x2*)(Ob + 32 + 8 * a + 4 * h) = o1;
    }
  };

  stage_dma(kvof(0), 0);
  stage_dma(kvof(1), 1);

  for (int f = 0; f < 34; ++f) {
    if (f + 1 < 34) asm volatile("s_waitcnt vmcnt(4)" ::: "memory");
    else            asm volatile("s_waitcnt vmcnt(0)" ::: "memory");
    __builtin_amdgcn_s_barrier();
    __builtin_amdgcn_sched_barrier(0);
    if (f + 2 < 34) stage_dma(kvof(f + 2), (f + 2) % 3);
    const u16* base = &lKV[f % 3][0];
    const int kv0 = kvof(f);

    if (kv0 <= qbase + 31) {                     // wave-uniform causal skip
      // ---- swapped QK^T: S^T[kv][q], one q column per lane ----
      f32x16 st0, st1;
#pragma unroll
      for (int i = 0; i < 16; i++) { st0[i] = 0.f; st1[i] = 0.f; }
      __builtin_amdgcn_s_setprio(1);
#pragma unroll
      for (int ks = 0; ks < 4; ks++) {
        const int sl = 2 * ks + h;
        s8v a0 = *(const s8v*)&base[(sl * 64 + (l31 ^ sl)) * 8];
        s8v a1 = *(const s8v*)&base[(sl * 64 + ((32 + l31) ^ sl)) * 8];
        st0 = __builtin_amdgcn_mfma_f32_32x32x16_bf16(a0, qf[ks], st0, 0, 0, 0);
        st1 = __builtin_amdgcn_mfma_f32_32x32x16_bf16(a1, qf[ks], st1, 0, 0, 0);
      }
      __builtin_amdgcn_s_setprio(0);
      // ---- causal mask (diagonal tiles only) ----
      if (kv0 + 63 > qbase) {
        const int dq = qbase + l31 - kv0;
#pragma unroll
        for (int r = 0; r < 16; r++) {
          const int kl = (r & 3) + 8 * (r >> 2) + 4 * h;
          if (kl > dq) st0[r] = -1e30f;
          if (kl + 32 > dq) st1[r] = -1e30f;
        }
      }
      // ---- online softmax: 4-partial tree max (depth ~7 vs 31) ----
      float p0 = fmaxf(st0[0], st1[0]);
      float p1 = fmaxf(st0[1], st1[1]);
      float p2 = fmaxf(st0[2], st1[2]);
      float p3 = fmaxf(st0[3], st1[3]);
#pragma unroll
      for (int r = 4; r < 16; r += 4) {
        p0 = fmaxf(p0, fmaxf(st0[r],     st1[r]));
        p1 = fmaxf(p1, fmaxf(st0[r + 1], st1[r + 1]));
        p2 = fmaxf(p2, fmaxf(st0[r + 2], st1[r + 2]));
        p3 = fmaxf(p3, fmaxf(st0[r + 3], st1[r + 3]));
      }
      float mx = fmaxf(fmaxf(p0, p1), fmaxf(p2, p3));
      mx = fmaxf(mx, __shfl_xor(mx, 32));
      if (!__all(mx <= mrun + 11.0f)) {          // defer-max (T13)
        const float mnew = fmaxf(mrun, mx);
        const float fsc = exp2f(mrun - mnew);
        lrun *= fsc;
#pragma unroll
        for (int r = 0; r < 16; r++) { accO0[r] *= fsc; accO1[r] *= fsc; }
        mrun = mnew;
      }
      // ---- exp + 4-partial tree sum (depth ~9 vs 32) ----
      float s0 = 0.f, s1 = 0.f, s2 = 0.f, s3 = 0.f;
#pragma unroll
      for (int r = 0; r < 16; r += 4) {
        st0[r]     = exp2f(st0[r]     - mrun); s0 += st0[r];
        st0[r + 1] = exp2f(st0[r + 1] - mrun); s1 += st0[r + 1];
        st0[r + 2] = exp2f(st0[r + 2] - mrun); s2 += st0[r + 2];
        st0[r + 3] = exp2f(st0[r + 3] - mrun); s3 += st0[r + 3];
        st1[r]     = exp2f(st1[r]     - mrun); s0 += st1[r];
        st1[r + 1] = exp2f(st1[r + 1] - mrun); s1 += st1[r + 1];
        st1[r + 2] = exp2f(st1[r + 2] - mrun); s2 += st1[r + 2];
        st1[r + 3] = exp2f(st1[r + 3] - mrun); s3 += st1[r + 3];
      }
      float s = (s0 + s1) + (s2 + s3);
      s += __shfl_xor(s, 32);
      lrun += s;
      // ---- P -> bf16 in-register ----
      u32 W0[8], W1[8];
#pragma unroll
      for (int a = 0; a < 4; a++) {
        W0[2 * a]     = cvtpk(st0[4 * a], st0[4 * a + 1]);
        W0[2 * a + 1] = cvtpk(st0[4 * a + 2], st0[4 * a + 3]);
        W1[2 * a]     = cvtpk(st1[4 * a], st1[4 * a + 1]);
        W1[2 * a + 1] = cvtpk(st1[4 * a + 2], st1[4 * a + 3]);
      }
      // ---- PV: O^T[dh][q] += Vt @ P, B-frag via permlane32_swap ----
      __builtin_amdgcn_s_setprio(1);
#pragma unroll
      for (int ks = 0; ks < 4; ks++) {
        const int kp = ks & 1;
        u32 x0 = (ks < 2) ? W0[4 * kp]     : W1[4 * kp];
        u32 y0 = (ks < 2) ? W0[4 * kp + 2] : W1[4 * kp + 2];
        u32 x1 = (ks < 2) ? W0[4 * kp + 1] : W1[4 * kp + 1];
        u32 y1 = (ks < 2) ? W0[4 * kp + 3] : W1[4 * kp + 3];
        plswap(x0, y0);
        plswap(x1, y1);
        union { u32 u[4]; s8v v; } fb;
        fb.u[0] = x0; fb.u[1] = x1; fb.u[2] = y0; fb.u[3] = y1;
        const int sl = 2 * ks + h;
        s8v va0 = *(const s8v*)&base[4096 + (sl * 64 + (l31 ^ sl)) * 8];
        s8v va1 = *(const s8v*)&base[4096 + (sl * 64 + ((32 + l31) ^ sl)) * 8];
        accO0 = __builtin_amdgcn_mfma_f32_32x32x16_bf16(va0, fb.v, accO0, 0, 0, 0);
        accO1 = __builtin_amdgcn_mfma_f32_32x32x16_bf16(va1, fb.v, accO1, 0, 0, 0);
      }
      __builtin_amdgcn_s_setprio(0);
    }

    if (f == n0 - 1) {                           // half boundary: flush + reset
      epilogue();
      qbase = (15 - pair) * 128 + w * 32;
      loadQ();
#pragma unroll
      for (int i = 0; i < 16; i++) { accO0[i] = 0.f; accO1[i] = 0.f; }
      mrun = -1e30f; lrun = 0.f;
    }
  }
  epilogue();
}

extern "C" void kernel_launch(void* const* d_in, const int* in_sizes, int n_in,
                              void* d_out, int out_size, void* d_ws, size_t ws_size,
                              hipStream_t stream) {
  const float* x      = (const float*)d_in[0];
  const float* w_attn = (const float*)d_in[1];
  const float* b_attn = (const float*)d_in[2];
  const float* w_proj = (const float*)d_in[3];
  const float* b_proj = (const float*)d_in[4];
  float* out = (float*)d_out;

  u16* ws  = (u16*)d_ws;
  u16* xb  = ws;                   // x bf16 [8192][1024]; reused as attn-out
  u16* wTa = xb + 8388608;         // w_attn^T bf16 [3072][1024]
  u16* wTp = wTa + 3145728;        // w_proj^T bf16 [1024][1024]
  u16* qb  = wTp + 1048576;        // [64 bh][2048][64], pre-scaled 0.125*log2e
  u16* kb  = qb + 8388608;         // [64 bh][2048][64]
  u16* vb  = kb + 8388608;         // [64 bh][64][2048]  (transposed)

  k_cvt<<<8192, 256, 0, stream>>>(x, xb, 2097152);
  k_tr<<<dim3(96, 32), dim3(32, 8), 0, stream>>>(w_attn, wTa, 1024, 3072);
  k_tr<<<dim3(32, 32), dim3(32, 8), 0, stream>>>(w_proj, wTp, 1024, 1024);
  k_gemm<0><<<dim3(24, 64), 256, 0, stream>>>(xb, wTa, b_attn, qb, kb, vb, nullptr, 8192, 3072, 1024);
  k_attn<<<512, 256, 0, stream>>>(qb, kb, vb, xb);
  k_gemm<1><<<dim3(8, 64), 256, 0, stream>>>(xb, wTp, b_proj, nullptr, nullptr, nullptr, out, 8192, 1024, 1024);
}

// Round 12
// 184.653 us; speedup vs baseline: 1.0687x; 1.0687x over previous
//
#include <hip/hip_runtime.h>

// GPT-2 attention block, B=4 S=2048 D=1024 H=16 DH=64, f32 in/out.
// GEMMs (R4-proven, FROZEN): 16x16x32 bf16 MFMA, 128x128 tile, BK=32, 4 waves,
//   3 LDS buffers, counted vmcnt(4), source-side XOR-swizzled gll16 staging.
// Attention (R12 = best-known R3 structure + tree reductions):
//   reg-staged 2-buf 32KB LDS (4 blocks/CU), lgkmcnt(0)+raw barrier keeps
//   prefetch global loads in flight across barriers, grid 1024 LPT,
//   swapped 32x32 MFMA, in-register softmax, 4-partial tree max/sum.
// Layouts (gfx950):
//   16x16x32: A[l&15][8*(l>>4)+e], B[l&15][8*(l>>4)+e], D[4*(l>>4)+r][l&15]
//   32x32x16: A[l&31][8*(l>>5)+e], B[l&31][8*(l>>5)+e],
//             D[(r&3)+8*(r>>2)+4*(l>>5)][l&31]
// LESSON (R9): 256^2/8-wave acc needs ~200 VGPR -> __launch_bounds__ minwave
//   >=4 forces full accumulator spill (VGPR=64, 1.4GB scratch). Do not retry.
// LESSON (R11): attn is TLP-fed (VALU/latency-bound): 512-block grid = 2/CU
//   residency lost 20% perf despite perfect balance. Keep grid >= 3-4x CU.

typedef short  s8v   __attribute__((ext_vector_type(8)));  // 8 bf16 (16B)
typedef float  f32x4 __attribute__((ext_vector_type(4)));
typedef float  f32x16 __attribute__((ext_vector_type(16)));
typedef unsigned short u16;
typedef u16    u16x4 __attribute__((ext_vector_type(4)));
typedef unsigned int u32;
typedef u32    u32x2 __attribute__((ext_vector_type(2)));

__device__ __forceinline__ u16 f2b(float f) {
  union { float f; unsigned u; } v; v.f = f;
  unsigned r = v.u + 0x7FFFu + ((v.u >> 16) & 1u);   // RNE
  return (u16)(r >> 16);
}
__device__ __forceinline__ u32 cvtpk(float lo, float hi) {   // bf16(lo)|bf16(hi)<<16
  u32 r; asm("v_cvt_pk_bf16_f32 %0, %1, %2" : "=v"(r) : "v"(lo), "v"(hi)); return r;
}
__device__ __forceinline__ void plswap(u32 &d, u32 &s) {
  asm volatile("v_permlane32_swap_b32 %0, %1" : "+v"(d), "+v"(s));
}
__device__ __forceinline__ void gll16(const void* g, void* l) {
  __builtin_amdgcn_global_load_lds((const __attribute__((address_space(1))) void*)g,
                                   (__attribute__((address_space(3))) void*)l, 16, 0, 0);
}

#define QSCALE 0.18033688011112042f   // 0.125 * log2(e): softmax in exp2 domain

// ---------------- f32 -> bf16 elementwise ----------------
__global__ __launch_bounds__(256) void k_cvt(const float* __restrict__ in,
                                             u16* __restrict__ out, int n4) {
  int t = blockIdx.x * 256 + threadIdx.x;
  if (t < n4) {
    f32x4 f = ((const f32x4*)in)[t];
    u16x4 o;
    o[0] = f2b(f[0]); o[1] = f2b(f[1]); o[2] = f2b(f[2]); o[3] = f2b(f[3]);
    ((u16x4*)out)[t] = o;
  }
}

// ---------------- f32 [R][C] -> bf16 [C][R] transpose ----------------
__global__ __launch_bounds__(256) void k_tr(const float* __restrict__ in,
                                            u16* __restrict__ out, int R, int C) {
  __shared__ float tile[32][33];
  int c0 = blockIdx.x * 32, r0 = blockIdx.y * 32;
  int tx = threadIdx.x, ty = threadIdx.y;
#pragma unroll
  for (int j = 0; j < 4; j++)
    tile[ty + j * 8][tx] = in[(size_t)(r0 + ty + j * 8) * C + c0 + tx];
  __syncthreads();
#pragma unroll
  for (int j = 0; j < 4; j++)
    out[(size_t)(c0 + ty + j * 8) * R + r0 + tx] = f2b(tile[tx][ty + j * 8]);
}

// ---- one K-tile of MFMA work: 8 swizzled ds_read_b128 + 16 MFMA (setprio'd) ----
__device__ __forceinline__ void gemm_tile(const u16* bA, const u16* bB,
                                          f32x4 (&acc)[4][4],
                                          int wr, int wc, int lr, int lg) {
  s8v af[4], bfr[4];
#pragma unroll
  for (int m = 0; m < 4; m++) {
    const int row = wr + m * 16 + lr;
    af[m] = *(const s8v*)&bA[row * 32 + (lg ^ ((row >> 1) & 3)) * 8];
  }
#pragma unroll
  for (int n = 0; n < 4; n++) {
    const int row = wc + n * 16 + lr;
    bfr[n] = *(const s8v*)&bB[row * 32 + (lg ^ ((row >> 1) & 3)) * 8];
  }
  __builtin_amdgcn_s_setprio(1);
#pragma unroll
  for (int m = 0; m < 4; m++)
#pragma unroll
    for (int n = 0; n < 4; n++)
      acc[m][n] = __builtin_amdgcn_mfma_f32_16x16x32_bf16(af[m], bfr[n], acc[m][n], 0, 0, 0);
  __builtin_amdgcn_s_setprio(0);
}

// ---------------- bf16 GEMM: C[M,N] = A[M,K] @ Bt[N,K]^T (+bias) ----------------
template <int EPI>
__global__ __launch_bounds__(256, 3) void k_gemm(
    const u16* __restrict__ A, const u16* __restrict__ Bt,
    const float* __restrict__ bias,
    u16* __restrict__ qb, u16* __restrict__ kb, u16* __restrict__ vb,
    float* __restrict__ outf, int M, int N, int K) {
  __shared__ u16 lA[3][4096];     // [buf][128 rows][32 cols], 16B-cell swizzled
  __shared__ u16 lB[3][4096];
  const int tid = threadIdx.x;
  const int lane = tid & 63, w = tid >> 6;
  const int wr = (w >> 1) * 64, wc = (w & 1) * 64;
  const int lr = lane & 15, lg = lane >> 4;

  const int nwg = gridDim.x * gridDim.y;
  const int bid = blockIdx.y * gridDim.x + blockIdx.x;
  const int swz = (bid & 7) * (nwg >> 3) + (bid >> 3);
  const int m0 = (swz / gridDim.x) * 128, n0 = (swz % gridDim.x) * 128;

  const int rr = lane >> 2;
  const int cb = ((lane & 3) ^ ((lane >> 3) & 3)) * 16;
  const size_t K2 = (size_t)K * 2;
  const char* gAc = (const char*)A + (size_t)m0 * K2;
  const char* gBc = (const char*)Bt + (size_t)n0 * K2;

  auto stage = [&](int kt, int buf) {
    const size_t ko = (size_t)kt * 64 + cb;
    char* dA = (char*)&lA[buf][0];
    char* dB = (char*)&lB[buf][0];
    gll16(gAc + (size_t)(32 * w + rr) * K2 + ko,      dA + (2 * w) * 1024);
    gll16(gAc + (size_t)(32 * w + 16 + rr) * K2 + ko, dA + (2 * w + 1) * 1024);
    gll16(gBc + (size_t)(32 * w + rr) * K2 + ko,      dB + (2 * w) * 1024);
    gll16(gBc + (size_t)(32 * w + 16 + rr) * K2 + ko, dB + (2 * w + 1) * 1024);
  };

  f32x4 acc[4][4];
  f32x4 zz = {0.f, 0.f, 0.f, 0.f};
#pragma unroll
  for (int m = 0; m < 4; m++)
#pragma unroll
    for (int n = 0; n < 4; n++) acc[m][n] = zz;

  const int nk = K / 32;
  stage(0, 0);
  if (nk > 1) stage(1, 1);

#define STEP(T, CB, SB)                                                     \
  if ((T) < nk) {                                                           \
    if ((T) + 1 < nk) { asm volatile("s_waitcnt vmcnt(4)" ::: "memory"); }  \
    else              { asm volatile("s_waitcnt vmcnt(0)" ::: "memory"); }  \
    __builtin_amdgcn_s_barrier();                                           \
    __builtin_amdgcn_sched_barrier(0);                                      \
    if ((T) + 2 < nk) stage((T) + 2, (SB));                                 \
    gemm_tile(&lA[(CB)][0], &lB[(CB)][0], acc, wr, wc, lr, lg);             \
  }

  for (int t0 = 0; t0 < nk; t0 += 3) {
    STEP(t0,     0, 2)
    STEP(t0 + 1, 1, 0)
    STEP(t0 + 2, 2, 1)
  }
#undef STEP

#pragma unroll
  for (int m = 0; m < 4; m++) {
#pragma unroll
    for (int n = 0; n < 4; n++) {
      const int col = n0 + wc + n * 16 + lr;
      const float bb = bias[col];
      const int row0 = m0 + wr + m * 16 + 4 * lg;
      if (EPI == 0) {
        const int which = col >> 10, d = col & 1023, h = d >> 6, dh = d & 63;
        if (which == 2) {
          const int b = row0 >> 11, s = row0 & 2047;
          u16x4 ov;
#pragma unroll
          for (int r = 0; r < 4; r++) ov[r] = f2b(acc[m][n][r] + bb);
          *(u16x4*)(vb + ((size_t)((b * 16 + h) * 64 + dh)) * 2048 + s) = ov;
        } else {
          u16* dst = which == 0 ? qb : kb;
          const float sc = which == 0 ? QSCALE : 1.0f;
#pragma unroll
          for (int r = 0; r < 4; r++) {
            const int row = row0 + r;
            const int b = row >> 11, s = row & 2047;
            dst[(size_t)((b * 16 + h) * 2048 + s) * 64 + dh] = f2b((acc[m][n][r] + bb) * sc);
          }
        }
      } else {
#pragma unroll
        for (int r = 0; r < 4; r++)
          outf[(size_t)(row0 + r) * N + col] = acc[m][n][r] + bb;
      }
    }
  }
}

// ---------------- flash attention, causal, swapped 32x32 MFMA, in-reg softmax ----
// R3-proven structure: grid 1024 (bh,qt) LPT, reg-staged 2-buf 32KB LDS,
// lgkmcnt(0)+raw barrier (prefetch stays in flight), + tree reductions.
__global__ __launch_bounds__(256, 3) void k_attn(
    const u16* __restrict__ Q, const u16* __restrict__ K,
    const u16* __restrict__ Vt, u16* __restrict__ O) {
  __shared__ u16 lKV[2][8192];     // [buf][ K: 4096 u16 | V: 4096 u16 ] = 32 KB
  const int x = blockIdx.x;
  const int bh = ((x & 7) << 3) | ((x >> 3) & 7);
  const int qt = 15 - (x >> 6);
  const int tid = threadIdx.x, lane = tid & 63, w = tid >> 6;
  const int l31 = lane & 31, h = lane >> 5;
  const int qbase = qt * 128 + w * 32;
  const u16* Kb = K + (size_t)bh * 2048 * 64;
  const u16* Vb = Vt + (size_t)bh * 64 * 2048;

  const int skv = tid >> 2;          // K: kv row / V: dh row
  const int ssl = (tid & 3) * 2;     // first of two 16B slots

  s8v kR0, kR1, vR0, vR1;
  auto pref = [&](int kv0) {
    const u16* gk = Kb + (size_t)(kv0 + skv) * 64 + ssl * 8;
    const u16* gv = Vb + (size_t)skv * 2048 + kv0 + ssl * 8;
    kR0 = *(const s8v*)gk; kR1 = *(const s8v*)(gk + 8);
    vR0 = *(const s8v*)gv; vR1 = *(const s8v*)(gv + 8);
  };
  auto stage = [&](int buf) {
    u16* base = &lKV[buf][0];
    *(s8v*)&base[(ssl * 64 + (skv ^ ssl)) * 8] = kR0;
    *(s8v*)&base[((ssl + 1) * 64 + (skv ^ (ssl + 1))) * 8] = kR1;
    *(s8v*)&base[4096 + (ssl * 64 + (skv ^ ssl)) * 8] = vR0;
    *(s8v*)&base[4096 + ((ssl + 1) * 64 + (skv ^ (ssl + 1))) * 8] = vR1;
  };

  // Q B-frags: lane l -> q col = l31, k(dh) = ks*16 + 8h + e
  s8v qf[4];
#pragma unroll
  for (int ks = 0; ks < 4; ks++)
    qf[ks] = *(const s8v*)(Q + (size_t)(bh * 2048 + qbase + l31) * 64 + ks * 16 + 8 * h);

  f32x16 accO0, accO1;
#pragma unroll
  for (int i = 0; i < 16; i++) { accO0[i] = 0.f; accO1[i] = 0.f; }
  float mrun = -1e30f, lrun = 0.f;

  const int ntile = 2 * qt + 2;
  pref(0); stage(0);
  if (ntile > 1) pref(64);

  for (int t = 0; t < ntile; ++t) {
    const int kv0 = t * 64;
    // raw barrier: drain own ds_writes (lgkm) but leave prefetch loads in flight
    asm volatile("s_waitcnt lgkmcnt(0)" ::: "memory");
    __builtin_amdgcn_s_barrier();
    __builtin_amdgcn_sched_barrier(0);
    const u16* base = &lKV[t & 1][0];

    if (kv0 <= qbase + 31) {               // wave-uniform causal skip
      // ---- swapped QK^T: S^T[kv][q], one q column per lane ----
      f32x16 st0, st1;
#pragma unroll
      for (int i = 0; i < 16; i++) { st0[i] = 0.f; st1[i] = 0.f; }
      __builtin_amdgcn_s_setprio(1);
#pragma unroll
      for (int ks = 0; ks < 4; ks++) {
        const int sl = 2 * ks + h;
        s8v a0 = *(const s8v*)&base[(sl * 64 + (l31 ^ sl)) * 8];
        s8v a1 = *(const s8v*)&base[(sl * 64 + ((32 + l31) ^ sl)) * 8];
        st0 = __builtin_amdgcn_mfma_f32_32x32x16_bf16(a0, qf[ks], st0, 0, 0, 0);
        st1 = __builtin_amdgcn_mfma_f32_32x32x16_bf16(a1, qf[ks], st1, 0, 0, 0);
      }
      __builtin_amdgcn_s_setprio(0);
      // ---- causal mask (diagonal tiles only) ----
      if (kv0 + 63 > qbase) {
        const int dq = qbase + l31 - kv0;  // kv_local <= dq allowed
#pragma unroll
        for (int r = 0; r < 16; r++) {
          const int kl = (r & 3) + 8 * (r >> 2) + 4 * h;
          if (kl > dq) st0[r] = -1e30f;
          if (kl + 32 > dq) st1[r] = -1e30f;
        }
      }
      // ---- online softmax: 4-partial tree max (depth ~7 vs 31) ----
      float p0 = fmaxf(st0[0], st1[0]);
      float p1 = fmaxf(st0[1], st1[1]);
      float p2 = fmaxf(st0[2], st1[2]);
      float p3 = fmaxf(st0[3], st1[3]);
#pragma unroll
      for (int r = 4; r < 16; r += 4) {
        p0 = fmaxf(p0, fmaxf(st0[r],     st1[r]));
        p1 = fmaxf(p1, fmaxf(st0[r + 1], st1[r + 1]));
        p2 = fmaxf(p2, fmaxf(st0[r + 2], st1[r + 2]));
        p3 = fmaxf(p3, fmaxf(st0[r + 3], st1[r + 3]));
      }
      float mx = fmaxf(fmaxf(p0, p1), fmaxf(p2, p3));
      mx = fmaxf(mx, __shfl_xor(mx, 32));
      if (!__all(mx <= mrun + 11.0f)) {    // defer-max (T13)
        const float mnew = fmaxf(mrun, mx);
        const float fsc = exp2f(mrun - mnew);
        lrun *= fsc;
#pragma unroll
        for (int r = 0; r < 16; r++) { accO0[r] *= fsc; accO1[r] *= fsc; }
        mrun = mnew;
      }
      // ---- exp + 4-partial tree sum (depth ~9 vs 32) ----
      float s0 = 0.f, s1 = 0.f, s2 = 0.f, s3 = 0.f;
#pragma unroll
      for (int r = 0; r < 16; r += 4) {
        st0[r]     = exp2f(st0[r]     - mrun); s0 += st0[r];
        st0[r + 1] = exp2f(st0[r + 1] - mrun); s1 += st0[r + 1];
        st0[r + 2] = exp2f(st0[r + 2] - mrun); s2 += st0[r + 2];
        st0[r + 3] = exp2f(st0[r + 3] - mrun); s3 += st0[r + 3];
        st1[r]     = exp2f(st1[r]     - mrun); s0 += st1[r];
        st1[r + 1] = exp2f(st1[r + 1] - mrun); s1 += st1[r + 1];
        st1[r + 2] = exp2f(st1[r + 2] - mrun); s2 += st1[r + 2];
        st1[r + 3] = exp2f(st1[r + 3] - mrun); s3 += st1[r + 3];
      }
      float s = (s0 + s1) + (s2 + s3);
      s += __shfl_xor(s, 32);
      lrun += s;
      // ---- P -> bf16 in-register ----
      u32 W0[8], W1[8];
#pragma unroll
      for (int a = 0; a < 4; a++) {
        W0[2 * a]     = cvtpk(st0[4 * a], st0[4 * a + 1]);
        W0[2 * a + 1] = cvtpk(st0[4 * a + 2], st0[4 * a + 3]);
        W1[2 * a]     = cvtpk(st1[4 * a], st1[4 * a + 1]);
        W1[2 * a + 1] = cvtpk(st1[4 * a + 2], st1[4 * a + 3]);
      }
      // ---- PV: O^T[dh][q] += Vt @ P, B-frag via permlane32_swap ----
      __builtin_amdgcn_s_setprio(1);
#pragma unroll
      for (int ks = 0; ks < 4; ks++) {
        const int kp = ks & 1;
        u32 x0 = (ks < 2) ? W0[4 * kp]     : W1[4 * kp];
        u32 y0 = (ks < 2) ? W0[4 * kp + 2] : W1[4 * kp + 2];
        u32 x1 = (ks < 2) ? W0[4 * kp + 1] : W1[4 * kp + 1];
        u32 y1 = (ks < 2) ? W0[4 * kp + 3] : W1[4 * kp + 3];
        plswap(x0, y0);
        plswap(x1, y1);
        union { u32 u[4]; s8v v; } fb;
        fb.u[0] = x0; fb.u[1] = x1; fb.u[2] = y0; fb.u[3] = y1;
        const int sl = 2 * ks + h;
        s8v va0 = *(const s8v*)&base[4096 + (sl * 64 + (l31 ^ sl)) * 8];
        s8v va1 = *(const s8v*)&base[4096 + (sl * 64 + ((32 + l31) ^ sl)) * 8];
        accO0 = __builtin_amdgcn_mfma_f32_32x32x16_bf16(va0, fb.v, accO0, 0, 0, 0);
        accO1 = __builtin_amdgcn_mfma_f32_32x32x16_bf16(va1, fb.v, accO1, 0, 0, 0);
      }
      __builtin_amdgcn_s_setprio(0);
    }
    if (t + 1 < ntile) {
      stage((t + 1) & 1);                  // auto vmcnt wait on pref(t+1) regs
      if (t + 2 < ntile) pref((t + 2) * 64);
    }
  }

  // ---- epilogue: O = O^T / l, merge heads, 8B stores ----
  const int b_ = bh >> 4, h_ = bh & 15;
  const float rinv = 1.0f / lrun;
  u16* Ob = O + (size_t)(b_ * 2048 + qbase + l31) * 1024 + h_ * 64;
#pragma unroll
  for (int a = 0; a < 4; a++) {
    u32x2 o0, o1;
    o0[0] = cvtpk(accO0[4 * a] * rinv, accO0[4 * a + 1] * rinv);
    o0[1] = cvtpk(accO0[4 * a + 2] * rinv, accO0[4 * a + 3] * rinv);
    o1[0] = cvtpk(accO1[4 * a] * rinv, accO1[4 * a + 1] * rinv);
    o1[1] = cvtpk(accO1[4 * a + 2] * rinv, accO1[4 * a + 3] * rinv);
    *(u32x2*)(Ob + 8 * a + 4 * h) = o0;
    *(u32x2*)(Ob + 32 + 8 * a + 4 * h) = o1;
  }
}

extern "C" void kernel_launch(void* const* d_in, const int* in_sizes, int n_in,
                              void* d_out, int out_size, void* d_ws, size_t ws_size,
                              hipStream_t stream) {
  const float* x      = (const float*)d_in[0];
  const float* w_attn = (const float*)d_in[1];
  const float* b_attn = (const float*)d_in[2];
  const float* w_proj = (const float*)d_in[3];
  const float* b_proj = (const float*)d_in[4];
  float* out = (float*)d_out;

  u16* ws  = (u16*)d_ws;
  u16* xb  = ws;                   // x bf16 [8192][1024]; reused as attn-out
  u16* wTa = xb + 8388608;         // w_attn^T bf16 [3072][1024]
  u16* wTp = wTa + 3145728;        // w_proj^T bf16 [1024][1024]
  u16* qb  = wTp + 1048576;        // [64 bh][2048][64], pre-scaled 0.125*log2e
  u16* kb  = qb + 8388608;         // [64 bh][2048][64]
  u16* vb  = kb + 8388608;         // [64 bh][64][2048]  (transposed)

  k_cvt<<<8192, 256, 0, stream>>>(x, xb, 2097152);
  k_tr<<<dim3(96, 32), dim3(32, 8), 0, stream>>>(w_attn, wTa, 1024, 3072);
  k_tr<<<dim3(32, 32), dim3(32, 8), 0, stream>>>(w_proj, wTp, 1024, 1024);
  k_gemm<0><<<dim3(24, 64), 256, 0, stream>>>(xb, wTa, b_attn, qb, kb, vb, nullptr, 8192, 3072, 1024);
  k_attn<<<1024, 256, 0, stream>>>(qb, kb, vb, xb);
  k_gemm<1><<<dim3(8, 64), 256, 0, stream>>>(xb, wTp, b_proj, nullptr, nullptr, nullptr, out, 8192, 1024, 1024);
}